// Round 7
// baseline (87.560 us; speedup 1.0000x reference)
//
#include <hip/hip_runtime.h>

#define PHI     1.618033988749895f
#define INV_PHI 0.6180339887498949f

typedef _Float16 f16x8 __attribute__((ext_vector_type(8)));
typedef float    f32x4 __attribute__((ext_vector_type(4)));

__device__ __forceinline__ float phi_spiral(float v) {
    // sigmoid(v/phi) * (v*phi / (1+|v|));  phi_spiral(0) == 0 exactly
    float e = __expf(-v * INV_PHI);
    float s = __fdividef(1.0f, 1.0f + e);
    float g = __fdividef(v * PHI, 1.0f + fabsf(v));
    return s * g;
}

// ---------------- workspace layout ----------------
// fp16 elements from byte 0:
//   [0,16384)      stage-1 B frags: fid = ks*4+nt (ks<8, nt<4), K=256, N=64
//   [16384,20480)  stage-2 B frags: fid = ks*4+nt (ks<2, nt<4), K=64,  N=64
//   [20480,22528)  stage-3 B frags: fid = ks*2+nt (ks<2, nt<2), K=64,  N=32
// fp32 from byte 65536: b1pad[64], b2pad[64], b3pad[32]  (zero-padded)
#define WS_B1 0
#define WS_B2 16384
#define WS_B3 20480
#define WS_BIAS_BYTES 65536

// B-fragment lane layout for v_mfma_f32_16x16x32_f16 (verified, m89-m103):
// lane holds B[k][n], n = lane&15, k = (lane>>4)*8 + j.
__global__ void prep_kernel(
    const float* __restrict__ W_in, const float* __restrict__ b_in,
    const float* __restrict__ Wn,   const float* __restrict__ bn,
    const float* __restrict__ W_int,const float* __restrict__ b_int,
    _Float16* __restrict__ wsh, float* __restrict__ wsb)
{
    if (blockIdx.x == 11) {                      // padded biases
        const int t = threadIdx.x;
        if (t < 64)       wsb[t] = (t < 49)        ? b_in[t]        : 0.f;
        else if (t < 128) wsb[t] = (t - 64 < 49)   ? bn[t - 64]     : 0.f;
        else if (t < 160) wsb[t] = (t - 128 < 21)  ? b_int[t - 128] : 0.f;
        return;
    }
    const int g    = blockIdx.x * 256 + threadIdx.x;   // 0..2815
    const int lane = g & 63;
    const int fid  = g >> 6;                            // 0..43
    const int lr = lane & 15, lk = lane >> 4;
    f16x8 o;
    if (fid < 32) {                       // stage 1: W_in[49,256]
        const int ks = fid >> 2, nt = fid & 3;
        const int n = nt * 16 + lr, kb = ks * 32 + lk * 8;
#pragma unroll 8
        for (int j = 0; j < 8; ++j) {
            const int k = kb + j;
            o[j] = (_Float16)((n < 49) ? W_in[n * 256 + k] : 0.f);
        }
        *reinterpret_cast<f16x8*>(wsh + WS_B1 + (size_t)(fid * 64 + lane) * 8) = o;
    } else if (fid < 40) {                // stage 2: Wn flat [49,49] (m = k*7+h)
        const int f = fid - 32, ks = f >> 2, nt = f & 3;
        const int n = nt * 16 + lr, kb = ks * 32 + lk * 8;
#pragma unroll 8
        for (int j = 0; j < 8; ++j) {
            const int k = kb + j;
            o[j] = (_Float16)((n < 49 && k < 49) ? Wn[n * 49 + k] : 0.f);
        }
        *reinterpret_cast<f16x8*>(wsh + WS_B2 + (size_t)(f * 64 + lane) * 8) = o;
    } else {                              // stage 3: W_int[21,49]
        const int f = fid - 40, ks = f >> 1, nt = f & 1;
        const int n = nt * 16 + lr, kb = ks * 32 + lk * 8;
#pragma unroll 8
        for (int j = 0; j < 8; ++j) {
            const int k = kb + j;
            o[j] = (_Float16)((n < 21 && k < 49) ? W_int[n * 49 + k] : 0.f);
        }
        *reinterpret_cast<f16x8*>(wsh + WS_B3 + (size_t)(f * 64 + lane) * 8) = o;
    }
}

// 256 threads = 4 waves; 256 rows/block; wave w owns rows 64w..64w+63.
// Stage-1 A-fragments load DIRECTLY from global (coalesced 16 rows x 128B
// segments), cvt to fp16 in-register -> no x staging, no stage-1 barriers.
// LDS only carries h/comb (fp16, [256][72]) and integ (fp32, [256][25],
// stride 25 = bank-conflict-free LN reads). Two barriers total.
__global__ __launch_bounds__(256, 4)
__attribute__((amdgpu_waves_per_eu(4, 4)))
void seven_neurons_mfma(
    const float* __restrict__ x,
    const _Float16* __restrict__ wsh, const float* __restrict__ wsb,
    const float* __restrict__ gamma, const float* __restrict__ beta,
    const float* __restrict__ W_out, const float* __restrict__ b_out,
    float* __restrict__ out)
{
    __shared__ __align__(16) unsigned char ldsraw[256 * 72 * 2];
    _Float16* ldsH = reinterpret_cast<_Float16*>(ldsraw);
    float*    ldsF = reinterpret_cast<float*>(ldsraw);

    const int t = threadIdx.x;
    const int lane = t & 63, wv = t >> 6;
    const int lr = lane & 15, lk = lane >> 4;
    const size_t row0 = (size_t)blockIdx.x * 256;

    // ---- stage 1: h[256,49] = spiral(x @ W_in^T + b1), MFMA over K=256
    f32x4 acc1[4][4];
#pragma unroll 4
    for (int mi = 0; mi < 4; ++mi)
#pragma unroll 4
        for (int ni = 0; ni < 4; ++ni) acc1[mi][ni] = (f32x4){0.f, 0.f, 0.f, 0.f};

    // per-lane A base: row = row0 + wv*64 + lr, col base = lk*8
    const float* xa = x + (row0 + wv * 64 + lr) * 256 + lk * 8;

#pragma unroll 8
    for (int ks = 0; ks < 8; ++ks) {
        f16x8 bf[4];
#pragma unroll 4
        for (int nt = 0; nt < 4; ++nt)
            bf[nt] = *reinterpret_cast<const f16x8*>(
                wsh + WS_B1 + (size_t)((ks * 4 + nt) * 64 + lane) * 8);
#pragma unroll 4
        for (int mi = 0; mi < 4; ++mi) {
            const float4 lo = *reinterpret_cast<const float4*>(xa + mi * 4096 + ks * 32);
            const float4 hi = *reinterpret_cast<const float4*>(xa + mi * 4096 + ks * 32 + 4);
            const f16x8 a = { (_Float16)lo.x, (_Float16)lo.y, (_Float16)lo.z, (_Float16)lo.w,
                              (_Float16)hi.x, (_Float16)hi.y, (_Float16)hi.z, (_Float16)hi.w };
#pragma unroll 4
            for (int nt = 0; nt < 4; ++nt)
                acc1[mi][nt] = __builtin_amdgcn_mfma_f32_16x16x32_f16(
                    a, bf[nt], acc1[mi][nt], 0, 0, 0);
        }
    }

    // epilogue 1: h -> LDS fp16 [256][72], cols 49..63 exact 0 (wave-private)
    {
        float b1v[4];
#pragma unroll 4
        for (int nt = 0; nt < 4; ++nt) b1v[nt] = wsb[nt * 16 + lr];
#pragma unroll 4
        for (int mi = 0; mi < 4; ++mi)
#pragma unroll 4
            for (int nt = 0; nt < 4; ++nt)
#pragma unroll 4
                for (int r = 0; r < 4; ++r) {
                    const int row = wv * 64 + mi * 16 + lk * 4 + r;
                    const float v = phi_spiral(acc1[mi][nt][r] + b1v[nt]);
                    ldsH[row * 72 + nt * 16 + lr] = (_Float16)v;
                }
    }

    // ---- stage 2: comb[256,49] = spiral(h @ Wn_mat^T + b2), K=64
    f32x4 acc2[4][4];
#pragma unroll 4
    for (int mi = 0; mi < 4; ++mi)
#pragma unroll 4
        for (int ni = 0; ni < 4; ++ni) acc2[mi][ni] = (f32x4){0.f, 0.f, 0.f, 0.f};
#pragma unroll 2
    for (int ks = 0; ks < 2; ++ks) {
        f16x8 bf[4];
#pragma unroll 4
        for (int nt = 0; nt < 4; ++nt)
            bf[nt] = *reinterpret_cast<const f16x8*>(
                wsh + WS_B2 + (size_t)((ks * 4 + nt) * 64 + lane) * 8);
#pragma unroll 4
        for (int mi = 0; mi < 4; ++mi) {
            const f16x8 a = *reinterpret_cast<const f16x8*>(
                &ldsH[(wv * 64 + mi * 16 + lr) * 72 + ks * 32 + lk * 8]);
#pragma unroll 4
            for (int nt = 0; nt < 4; ++nt)
                acc2[mi][nt] = __builtin_amdgcn_mfma_f32_16x16x32_f16(
                    a, bf[nt], acc2[mi][nt], 0, 0, 0);
        }
    }
    // epilogue 2: comb overwrites h (own rows; in-wave DS ordering suffices)
    {
        float b2v[4];
#pragma unroll 4
        for (int nt = 0; nt < 4; ++nt) b2v[nt] = wsb[64 + nt * 16 + lr];
#pragma unroll 4
        for (int mi = 0; mi < 4; ++mi)
#pragma unroll 4
            for (int nt = 0; nt < 4; ++nt)
#pragma unroll 4
                for (int r = 0; r < 4; ++r) {
                    const int row = wv * 64 + mi * 16 + lk * 4 + r;
                    const float v = phi_spiral(acc2[mi][nt][r] + b2v[nt]);
                    ldsH[row * 72 + nt * 16 + lr] = (_Float16)v;
                }
    }

    // ---- stage 3: integ[256,21] = spiral(comb @ W_int^T + b3), K=64, N=32
    f32x4 acc3[4][2];
#pragma unroll 4
    for (int mi = 0; mi < 4; ++mi)
#pragma unroll 2
        for (int ni = 0; ni < 2; ++ni) acc3[mi][ni] = (f32x4){0.f, 0.f, 0.f, 0.f};
#pragma unroll 2
    for (int ks = 0; ks < 2; ++ks) {
        f16x8 bf[2];
#pragma unroll 2
        for (int nt = 0; nt < 2; ++nt)
            bf[nt] = *reinterpret_cast<const f16x8*>(
                wsh + WS_B3 + (size_t)((ks * 2 + nt) * 64 + lane) * 8);
#pragma unroll 4
        for (int mi = 0; mi < 4; ++mi) {
            const f16x8 a = *reinterpret_cast<const f16x8*>(
                &ldsH[(wv * 64 + mi * 16 + lr) * 72 + ks * 32 + lk * 8]);
#pragma unroll 2
            for (int nt = 0; nt < 2; ++nt)
                acc3[mi][nt] = __builtin_amdgcn_mfma_f32_16x16x32_f16(
                    a, bf[nt], acc3[mi][nt], 0, 0, 0);
        }
    }
    __syncthreads();   // all waves' comb reads done before fp32 overwrite
    // epilogue 3: integ -> LDS fp32 [256][25] (fp32: no rounding before LN)
    {
        float b3v[2];
#pragma unroll 2
        for (int nt = 0; nt < 2; ++nt) b3v[nt] = wsb[128 + nt * 16 + lr];
#pragma unroll 4
        for (int mi = 0; mi < 4; ++mi)
#pragma unroll 2
            for (int nt = 0; nt < 2; ++nt)
#pragma unroll 4
                for (int r = 0; r < 4; ++r) {
                    const int col = nt * 16 + lr;
                    const int row = wv * 64 + mi * 16 + lk * 4 + r;
                    if (col < 21)
                        ldsF[row * 25 + col] =
                            phi_spiral(acc3[mi][nt][r] + b3v[nt]);
                }
    }
    __syncthreads();

    // ---- LayerNorm(21) + out[4]: thread t owns row t (stride 25: no conflicts)
    {
        const float* my = ldsF + t * 25;
        float v[21];
#pragma unroll 21
        for (int o = 0; o < 21; ++o) v[o] = my[o];
        float mu = 0.f;
#pragma unroll 21
        for (int o = 0; o < 21; ++o) mu += v[o];
        mu *= (1.0f / 21.0f);
        float var = 0.f;
#pragma unroll 21
        for (int o = 0; o < 21; ++o) { float d = v[o] - mu; var = fmaf(d, d, var); }
        var *= (1.0f / 21.0f);
        const float rs = rsqrtf(var + 1e-5f);
#pragma unroll 21
        for (int o = 0; o < 21; ++o)
            v[o] = (v[o] - mu) * rs * gamma[o] + beta[o];
        float o4[4];
#pragma unroll 4
        for (int p = 0; p < 4; ++p) {
            float acc = b_out[p];
#pragma unroll 21
            for (int o = 0; o < 21; ++o) acc = fmaf(v[o], W_out[p * 21 + o], acc);
            o4[p] = acc;
        }
        *reinterpret_cast<float4*>(out + (row0 + t) * 4) =
            make_float4(o4[0], o4[1], o4[2], o4[3]);
    }
}

extern "C" void kernel_launch(void* const* d_in, const int* in_sizes, int n_in,
                              void* d_out, int out_size, void* d_ws, size_t ws_size,
                              hipStream_t stream) {
    const float* x     = (const float*)d_in[0];
    const float* W_in  = (const float*)d_in[1];
    const float* b_in  = (const float*)d_in[2];
    const float* Wn    = (const float*)d_in[3];
    const float* bn    = (const float*)d_in[4];
    const float* W_int = (const float*)d_in[5];
    const float* b_int = (const float*)d_in[6];
    const float* gamma = (const float*)d_in[7];
    const float* beta  = (const float*)d_in[8];
    const float* W_out = (const float*)d_in[9];
    const float* b_out = (const float*)d_in[10];
    float* out = (float*)d_out;

    _Float16* wsh = (_Float16*)d_ws;
    float*    wsb = (float*)((char*)d_ws + WS_BIAS_BYTES);

    prep_kernel<<<12, 256, 0, stream>>>(W_in, b_in, Wn, bn, W_int, b_int, wsh, wsb);

    const int B = in_sizes[0] / 256;          // 262144, multiple of 256
    seven_neurons_mfma<<<B / 256, 256, 0, stream>>>(
        x, wsh, wsb, gamma, beta, W_out, b_out, out);
}

// Round 8
// 71.095 us; speedup vs baseline: 1.2316x; 1.2316x over previous
//
#include <hip/hip_runtime.h>

#define PHI     1.618033988749895f
#define INV_PHI 0.6180339887498949f

typedef _Float16 f16x8 __attribute__((ext_vector_type(8)));
typedef float    f32x4 __attribute__((ext_vector_type(4)));

__device__ __forceinline__ float phi_spiral(float v) {
    // sigmoid(v/phi) * (v*phi/(1+|v|)) = v*phi / ((1+e^{-v/phi})(1+|v|))
    // one exp + ONE rcp (R7 had two)
    float e = __expf(-v * INV_PHI);
    float d = (1.0f + e) * (1.0f + fabsf(v));
    return __fdividef(v * PHI, d);
}

// ---------------- workspace layout ----------------
#define WS_B1 0
#define WS_B2 16384
#define WS_B3 20480
#define WS_BIAS_BYTES 65536

// B-fragment lane layout for v_mfma_f32_16x16x32_f16 (verified, m89-m103):
// lane holds B[k][n], n = lane&15, k = (lane>>4)*8 + j.
__global__ void prep_kernel(
    const float* __restrict__ W_in, const float* __restrict__ b_in,
    const float* __restrict__ Wn,   const float* __restrict__ bn,
    const float* __restrict__ W_int,const float* __restrict__ b_int,
    _Float16* __restrict__ wsh, float* __restrict__ wsb)
{
    if (blockIdx.x == 11) {                      // padded biases
        const int t = threadIdx.x;
        if (t < 64)       wsb[t] = (t < 49)        ? b_in[t]        : 0.f;
        else if (t < 128) wsb[t] = (t - 64 < 49)   ? bn[t - 64]     : 0.f;
        else if (t < 160) wsb[t] = (t - 128 < 21)  ? b_int[t - 128] : 0.f;
        return;
    }
    const int g    = blockIdx.x * 256 + threadIdx.x;   // 0..2815
    const int lane = g & 63;
    const int fid  = g >> 6;                            // 0..43
    const int lr = lane & 15, lk = lane >> 4;
    f16x8 o;
    if (fid < 32) {                       // stage 1: W_in[49,256]
        const int ks = fid >> 2, nt = fid & 3;
        const int n = nt * 16 + lr, kb = ks * 32 + lk * 8;
#pragma unroll 8
        for (int j = 0; j < 8; ++j) {
            const int k = kb + j;
            o[j] = (_Float16)((n < 49) ? W_in[n * 256 + k] : 0.f);
        }
        *reinterpret_cast<f16x8*>(wsh + WS_B1 + (size_t)(fid * 64 + lane) * 8) = o;
    } else if (fid < 40) {                // stage 2: Wn flat [49,49]
        const int f = fid - 32, ks = f >> 2, nt = f & 3;
        const int n = nt * 16 + lr, kb = ks * 32 + lk * 8;
#pragma unroll 8
        for (int j = 0; j < 8; ++j) {
            const int k = kb + j;
            o[j] = (_Float16)((n < 49 && k < 49) ? Wn[n * 49 + k] : 0.f);
        }
        *reinterpret_cast<f16x8*>(wsh + WS_B2 + (size_t)(f * 64 + lane) * 8) = o;
    } else {                              // stage 3: W_int[21,49]
        const int f = fid - 40, ks = f >> 1, nt = f & 1;
        const int n = nt * 16 + lr, kb = ks * 32 + lk * 8;
#pragma unroll 8
        for (int j = 0; j < 8; ++j) {
            const int k = kb + j;
            o[j] = (_Float16)((n < 21 && k < 49) ? W_int[n * 49 + k] : 0.f);
        }
        *reinterpret_cast<f16x8*>(wsh + WS_B3 + (size_t)(f * 64 + lane) * 8) = o;
    }
}

// 256 threads = 4 waves; 128 rows/block (32 rows/wave, mi<2); grid 2048.
// waves_per_eu(6,8): allocator caps at 85 VGPR -> 6 waves/SIMD resident
// (R7 had 4). Smaller per-wave tile = less register pressure + more
// independent HBM streams -> hides the ~900-cyc load latency that R6/R7
// stalled on. LDS 18.4 KB/block (h/comb fp16 [128][72], integ fp32 [128][25]
// overlaid) -> 6 blocks/CU fits easily.
__global__ __launch_bounds__(256)
__attribute__((amdgpu_waves_per_eu(6, 8)))
void seven_neurons_mfma(
    const float* __restrict__ x,
    const _Float16* __restrict__ wsh, const float* __restrict__ wsb,
    const float* __restrict__ gamma, const float* __restrict__ beta,
    const float* __restrict__ W_out, const float* __restrict__ b_out,
    float* __restrict__ out)
{
    __shared__ __align__(16) unsigned char ldsraw[128 * 72 * 2];
    _Float16* ldsH = reinterpret_cast<_Float16*>(ldsraw);
    float*    ldsF = reinterpret_cast<float*>(ldsraw);

    const int t = threadIdx.x;
    const int lane = t & 63, wv = t >> 6;
    const int lr = lane & 15, lk = lane >> 4;
    const size_t row0 = (size_t)blockIdx.x * 128;

    // ---- stage 1: h[128,49] = spiral(x @ W_in^T + b1), MFMA over K=256
    f32x4 acc1[2][4];
#pragma unroll 2
    for (int mi = 0; mi < 2; ++mi)
#pragma unroll 4
        for (int ni = 0; ni < 4; ++ni) acc1[mi][ni] = (f32x4){0.f, 0.f, 0.f, 0.f};

    const float* xa = x + (row0 + wv * 32 + lr) * 256 + lk * 8;

#pragma unroll 8
    for (int ks = 0; ks < 8; ++ks) {
        f16x8 bf[4];
#pragma unroll 4
        for (int nt = 0; nt < 4; ++nt)
            bf[nt] = *reinterpret_cast<const f16x8*>(
                wsh + WS_B1 + (size_t)((ks * 4 + nt) * 64 + lane) * 8);
#pragma unroll 2
        for (int mi = 0; mi < 2; ++mi) {
            const float4 lo = *reinterpret_cast<const float4*>(xa + mi * 4096 + ks * 32);
            const float4 hi = *reinterpret_cast<const float4*>(xa + mi * 4096 + ks * 32 + 4);
            const f16x8 a = { (_Float16)lo.x, (_Float16)lo.y, (_Float16)lo.z, (_Float16)lo.w,
                              (_Float16)hi.x, (_Float16)hi.y, (_Float16)hi.z, (_Float16)hi.w };
#pragma unroll 4
            for (int nt = 0; nt < 4; ++nt)
                acc1[mi][nt] = __builtin_amdgcn_mfma_f32_16x16x32_f16(
                    a, bf[nt], acc1[mi][nt], 0, 0, 0);
        }
    }

    // epilogue 1: h -> LDS fp16 [128][72], cols 49..63 exact 0 (wave-private)
    {
        float b1v[4];
#pragma unroll 4
        for (int nt = 0; nt < 4; ++nt) b1v[nt] = wsb[nt * 16 + lr];
#pragma unroll 2
        for (int mi = 0; mi < 2; ++mi)
#pragma unroll 4
            for (int nt = 0; nt < 4; ++nt)
#pragma unroll 4
                for (int r = 0; r < 4; ++r) {
                    const int row = wv * 32 + mi * 16 + lk * 4 + r;
                    const float v = phi_spiral(acc1[mi][nt][r] + b1v[nt]);
                    ldsH[row * 72 + nt * 16 + lr] = (_Float16)v;
                }
    }

    // ---- stage 2: comb[128,49] = spiral(h @ Wn^T + b2), K=64
    f32x4 acc2[2][4];
#pragma unroll 2
    for (int mi = 0; mi < 2; ++mi)
#pragma unroll 4
        for (int ni = 0; ni < 4; ++ni) acc2[mi][ni] = (f32x4){0.f, 0.f, 0.f, 0.f};
#pragma unroll 2
    for (int ks = 0; ks < 2; ++ks) {
        f16x8 bf[4];
#pragma unroll 4
        for (int nt = 0; nt < 4; ++nt)
            bf[nt] = *reinterpret_cast<const f16x8*>(
                wsh + WS_B2 + (size_t)((ks * 4 + nt) * 64 + lane) * 8);
#pragma unroll 2
        for (int mi = 0; mi < 2; ++mi) {
            const f16x8 a = *reinterpret_cast<const f16x8*>(
                &ldsH[(wv * 32 + mi * 16 + lr) * 72 + ks * 32 + lk * 8]);
#pragma unroll 4
            for (int nt = 0; nt < 4; ++nt)
                acc2[mi][nt] = __builtin_amdgcn_mfma_f32_16x16x32_f16(
                    a, bf[nt], acc2[mi][nt], 0, 0, 0);
        }
    }
    // epilogue 2: comb overwrites h (own rows; in-wave DS ordering suffices)
    {
        float b2v[4];
#pragma unroll 4
        for (int nt = 0; nt < 4; ++nt) b2v[nt] = wsb[64 + nt * 16 + lr];
#pragma unroll 2
        for (int mi = 0; mi < 2; ++mi)
#pragma unroll 4
            for (int nt = 0; nt < 4; ++nt)
#pragma unroll 4
                for (int r = 0; r < 4; ++r) {
                    const int row = wv * 32 + mi * 16 + lk * 4 + r;
                    const float v = phi_spiral(acc2[mi][nt][r] + b2v[nt]);
                    ldsH[row * 72 + nt * 16 + lr] = (_Float16)v;
                }
    }

    // ---- stage 3: integ[128,21] = spiral(comb @ W_int^T + b3), K=64, N=32
    f32x4 acc3[2][2];
#pragma unroll 2
    for (int mi = 0; mi < 2; ++mi)
#pragma unroll 2
        for (int ni = 0; ni < 2; ++ni) acc3[mi][ni] = (f32x4){0.f, 0.f, 0.f, 0.f};
#pragma unroll 2
    for (int ks = 0; ks < 2; ++ks) {
        f16x8 bf[2];
#pragma unroll 2
        for (int nt = 0; nt < 2; ++nt)
            bf[nt] = *reinterpret_cast<const f16x8*>(
                wsh + WS_B3 + (size_t)((ks * 2 + nt) * 64 + lane) * 8);
#pragma unroll 2
        for (int mi = 0; mi < 2; ++mi) {
            const f16x8 a = *reinterpret_cast<const f16x8*>(
                &ldsH[(wv * 32 + mi * 16 + lr) * 72 + ks * 32 + lk * 8]);
#pragma unroll 2
            for (int nt = 0; nt < 2; ++nt)
                acc3[mi][nt] = __builtin_amdgcn_mfma_f32_16x16x32_f16(
                    a, bf[nt], acc3[mi][nt], 0, 0, 0);
        }
    }
    __syncthreads();   // ldsH reads done before ldsF overwrite (strides alias)
    // epilogue 3: integ -> LDS fp32 [128][25] (stride 25: conflict-free)
    {
        float b3v[2];
#pragma unroll 2
        for (int nt = 0; nt < 2; ++nt) b3v[nt] = wsb[128 + nt * 16 + lr];
#pragma unroll 2
        for (int mi = 0; mi < 2; ++mi)
#pragma unroll 2
            for (int nt = 0; nt < 2; ++nt)
#pragma unroll 4
                for (int r = 0; r < 4; ++r) {
                    const int col = nt * 16 + lr;
                    const int row = wv * 32 + mi * 16 + lk * 4 + r;
                    if (col < 21)
                        ldsF[row * 25 + col] =
                            phi_spiral(acc3[mi][nt][r] + b3v[nt]);
                }
    }
    __syncthreads();

    // ---- LayerNorm(21) + out: 2 threads/row (r = t&127, half = t>>7)
    {
        const int r = t & 127, half = t >> 7;
        const float* my = ldsF + r * 25;
        float v[21];
#pragma unroll 21
        for (int o = 0; o < 21; ++o) v[o] = my[o];
        float mu = 0.f;
#pragma unroll 21
        for (int o = 0; o < 21; ++o) mu += v[o];
        mu *= (1.0f / 21.0f);
        float var = 0.f;
#pragma unroll 21
        for (int o = 0; o < 21; ++o) { float d = v[o] - mu; var = fmaf(d, d, var); }
        var *= (1.0f / 21.0f);
        const float rs = rsqrtf(var + 1e-5f);
#pragma unroll 21
        for (int o = 0; o < 21; ++o)
            v[o] = (v[o] - mu) * rs * gamma[o] + beta[o];
        float o2[2];
#pragma unroll 2
        for (int p = 0; p < 2; ++p) {
            const int pp = half * 2 + p;
            float acc = b_out[pp];
#pragma unroll 21
            for (int o = 0; o < 21; ++o) acc = fmaf(v[o], W_out[pp * 21 + o], acc);
            o2[p] = acc;
        }
        *reinterpret_cast<float2*>(out + (row0 + r) * 4 + half * 2) =
            make_float2(o2[0], o2[1]);
    }
}

extern "C" void kernel_launch(void* const* d_in, const int* in_sizes, int n_in,
                              void* d_out, int out_size, void* d_ws, size_t ws_size,
                              hipStream_t stream) {
    const float* x     = (const float*)d_in[0];
    const float* W_in  = (const float*)d_in[1];
    const float* b_in  = (const float*)d_in[2];
    const float* Wn    = (const float*)d_in[3];
    const float* bn    = (const float*)d_in[4];
    const float* W_int = (const float*)d_in[5];
    const float* b_int = (const float*)d_in[6];
    const float* gamma = (const float*)d_in[7];
    const float* beta  = (const float*)d_in[8];
    const float* W_out = (const float*)d_in[9];
    const float* b_out = (const float*)d_in[10];
    float* out = (float*)d_out;

    _Float16* wsh = (_Float16*)d_ws;
    float*    wsb = (float*)((char*)d_ws + WS_BIAS_BYTES);

    prep_kernel<<<12, 256, 0, stream>>>(W_in, b_in, Wn, bn, W_int, b_int, wsh, wsb);

    const int B = in_sizes[0] / 256;          // 262144, multiple of 128
    seven_neurons_mfma<<<B / 128, 256, 0, stream>>>(
        x, wsh, wsb, gamma, beta, W_out, b_out, out);
}